// Round 5
// baseline (67.122 us; speedup 1.0000x reference)
//
#include <hip/hip_runtime.h>

#define NDIM 64
#define NRANK 8
#define NK 16
#define CSTRIDE 641                 // floats per component: 1 + 64 + 512 + 64
#define ROWSTRIDE (CSTRIDE * NK)    // 10256 floats = 41024 B per row
#define QBYTES (ROWSTRIDE)          // 10256 B per wave quarter (by luck /4 in floats == bytes/4)
#define GRID_BLOCKS 768             // 3 blocks/CU * 256 CUs (LDS-limited residency)

// ---- DPP helpers --------------------------------------------------------

template <int CTRL>
__device__ __forceinline__ float dpp_mov(float x) {
  int t = __builtin_amdgcn_update_dpp(0, __builtin_bit_cast(int, x), CTRL,
                                      0xF, 0xF, true);
  return __builtin_bit_cast(float, t);
}

// sum across the 16-lane group (lane bits 0..3); all 16 lanes get the total
__device__ __forceinline__ void red16(float& x) {
  x += dpp_mov<0xB1>(x);   // quad_perm [1,0,3,2]  == xor 1
  x += dpp_mov<0x4E>(x);   // quad_perm [2,3,0,1]  == xor 2
  x += dpp_mov<0x141>(x);  // row_half_mirror      == xor 4
  x += dpp_mov<0x140>(x);  // row_mirror           == xor 8
}

// async global->LDS, 16 B per active lane; dst wave-uniform, src per-lane
__device__ __forceinline__ void gld_lds16(const void* g, void* l) {
  __builtin_amdgcn_global_load_lds(
      (const __attribute__((address_space(1))) void*)g,
      (__attribute__((address_space(3))) void*)l, 16, 0, 0);
}

// ---- kernel -------------------------------------------------------------
// Persistent grid-stride: 768 blocks, each processes rows b, b+768, ...
// Wave w stages EXACTLY its own quarter (bytes [10256w, 10256(w+1)) of the
// row) = 10 x 1KB chunks + one 16B tail — no duplication, no overrun, no
// cross-wave row dependency. After its LDS reads for row n retire, the wave
// issues the stage for row n+768 into the same region, overlapping HBM
// latency with the reduction/Cholesky/LSE tail.

__global__ __launch_bounds__(256) void gmm_nll_kernel(
    const float* __restrict__ pred, const float* __restrict__ label,
    float* __restrict__ out, int nb) {
  __shared__ float lds[ROWSTRIDE + 32];  // row floats + 32 LSE scratch
  const int tid = threadIdx.x;
  const int w = tid >> 6;       // wave id 0..3
  const int lane = tid & 63;
  const int kk = lane >> 4;     // component within wave
  const int de = lane & 15;     // dim-group within component

  const int k = 4 * w + kk;
  const int C0 = CSTRIDE * k;

  char* qdst = (char*)lds + (size_t)QBYTES * w;

  int b = blockIdx.x;

  // ---- prologue: issue stage + label loads for the first row ----
  {
    const char* qsrc =
        (const char*)(pred + (size_t)b * ROWSTRIDE) + QBYTES * w + 16 * lane;
#pragma unroll
    for (int t = 0; t < 10; ++t) gld_lds16(qsrc + 1024 * t, qdst + 1024 * t);
    if (lane == 0) gld_lds16(qsrc + 10240, qdst + 10240);
  }
  float lb_[4];
  {
    const float* lbl = label + (size_t)b * NDIM + de;
    lb_[0] = lbl[0]; lb_[1] = lbl[16]; lb_[2] = lbl[32]; lb_[3] = lbl[48];
  }

  for (;;) {
    // wait for this wave's staged quarter (and label regs) to land
    asm volatile("s_waitcnt vmcnt(0)" ::: "memory");

    // ---- accumulate cap / b / mahal over this lane's 4 dims ----
    float capL[NRANK][NRANK];  // lower triangle (s <= r) used
    float bv[NRANK];
#pragma unroll
    for (int r = 0; r < NRANK; ++r) {
      bv[r] = 0.f;
#pragma unroll
      for (int s = 0; s <= r; ++s) capL[r][s] = 0.f;
    }
    float mahal1 = 0.f, ldsum = 0.f;

#pragma unroll
    for (int i = 0; i < 4; ++i) {
      const int d = de + 16 * i;
      float mu = lds[C0 + 1 + d];
      float ldv = lds[C0 + 577 + d];   // 1 + 64 + 512
      float sd = __expf(-0.5f * ldv);  // sqrt(1/d)
      float diff = lb_[i] - mu;
      float u = diff * sd;
      mahal1 = fmaf(u, u, mahal1);
      ldsum += ldv;

      float v[NRANK];
#pragma unroll
      for (int r = 0; r < NRANK; ++r) v[r] = lds[C0 + 65 + 8 * d + r] * sd;
#pragma unroll
      for (int r = 0; r < NRANK; ++r) {
        bv[r] = fmaf(v[r], u, bv[r]);
#pragma unroll
        for (int s = 0; s <= r; ++s)
          capL[r][s] = fmaf(v[r], v[s], capL[r][s]);
      }
    }
    float pi = lds[C0];  // last LDS read of this row's data

    // all LDS reads of row n retired -> safe to DMA row n+GRID over them
    asm volatile("s_waitcnt lgkmcnt(0)" ::: "memory");

    const int nextb = b + GRID_BLOCKS;
    const bool more = nextb < nb;
    float lbn[4];
    if (more) {
      const char* qsrc = (const char*)(pred + (size_t)nextb * ROWSTRIDE) +
                         QBYTES * w + 16 * lane;
#pragma unroll
      for (int t = 0; t < 10; ++t) gld_lds16(qsrc + 1024 * t, qdst + 1024 * t);
      if (lane == 0) gld_lds16(qsrc + 10240, qdst + 10240);
      const float* lbl = label + (size_t)nextb * NDIM + de;
      lbn[0] = lbl[0]; lbn[1] = lbl[16]; lbn[2] = lbl[32]; lbn[3] = lbl[48];
    }

    // ---- reductions + per-component tail math (registers only) ----
    red16(mahal1);
    red16(ldsum);
#pragma unroll
    for (int r = 0; r < NRANK; ++r) {
      red16(bv[r]);
#pragma unroll
      for (int s = 0; s <= r; ++s) red16(capL[r][s]);
    }

#pragma unroll
    for (int r = 0; r < NRANK; ++r) capL[r][r] += 1.0f;

    // in-place Cholesky (lower), fully unrolled; rsqrt + deferred single log
    float invd[NRANK];
    float prodinv = 1.0f;
#pragma unroll
    for (int j = 0; j < NRANK; ++j) {
      float s = capL[j][j];
#pragma unroll
      for (int p = 0; p < j; ++p) s = fmaf(-capL[j][p], capL[j][p], s);
      float inv = __frsqrt_rn(s);  // 1/L_jj
      invd[j] = inv;
      prodinv *= inv;
#pragma unroll
      for (int i2 = j + 1; i2 < NRANK; ++i2) {
        float t = capL[i2][j];
#pragma unroll
        for (int p = 0; p < j; ++p) t = fmaf(-capL[i2][p], capL[j][p], t);
        capL[i2][j] = t * inv;
      }
    }
    float logdetL = -__logf(prodinv);  // sum log(L_jj)

    // forward solve L y = b, accumulate |y|^2
    float y[NRANK];
    float ysq = 0.f;
#pragma unroll
    for (int i2 = 0; i2 < NRANK; ++i2) {
      float t = bv[i2];
#pragma unroll
      for (int j = 0; j < i2; ++j) t = fmaf(-capL[i2][j], y[j], t);
      y[i2] = t * invd[i2];
      ysq = fmaf(y[i2], y[i2], ysq);
    }

    float mahal = mahal1 - ysq;
    float logdet = 2.0f * logdetL + ldsum;
    const float c_dim_log2pi = 117.62413225019810f;  // 64 * log(2*pi)
    float comp_lp = -0.5f * (c_dim_log2pi + logdet + mahal);

    if (de == 0) {
      lds[ROWSTRIDE + k] = pi;
      lds[ROWSTRIDE + 16 + k] = pi + comp_lp;
    }
    __syncthreads();

    // final logsumexp over the 16 components (wave 0, lanes 0..15)
    if (tid < 16) {
      float p = lds[ROWSTRIDE + tid];
      float t2 = lds[ROWSTRIDE + 16 + tid];

      float m1 = p;
      m1 = fmaxf(m1, dpp_mov<0xB1>(m1));
      m1 = fmaxf(m1, dpp_mov<0x4E>(m1));
      m1 = fmaxf(m1, dpp_mov<0x141>(m1));
      m1 = fmaxf(m1, dpp_mov<0x140>(m1));
      float e1 = __expf(p - m1);
      red16(e1);

      float m2 = t2;
      m2 = fmaxf(m2, dpp_mov<0xB1>(m2));
      m2 = fmaxf(m2, dpp_mov<0x4E>(m2));
      m2 = fmaxf(m2, dpp_mov<0x141>(m2));
      m2 = fmaxf(m2, dpp_mov<0x140>(m2));
      float e2 = __expf(t2 - m2);
      red16(e2);

      if (tid == 0) out[b] = (m1 + __logf(e1)) - (m2 + __logf(e2));
    }
    // order wave0's scratch reads before next iteration's scratch writes
    __syncthreads();

    if (!more) break;
    b = nextb;
    lb_[0] = lbn[0]; lb_[1] = lbn[1]; lb_[2] = lbn[2]; lb_[3] = lbn[3];
  }
}

extern "C" void kernel_launch(void* const* d_in, const int* in_sizes, int n_in,
                              void* d_out, int out_size, void* d_ws,
                              size_t ws_size, hipStream_t stream) {
  const float* pred = (const float*)d_in[0];
  const float* label = (const float*)d_in[1];
  float* out = (float*)d_out;
  const int nb = out_size;  // 8192
  gmm_nll_kernel<<<dim3(GRID_BLOCKS), dim3(256), 0, stream>>>(pred, label, out,
                                                              nb);
}

// Round 6
// 58.085 us; speedup vs baseline: 1.1556x; 1.1556x over previous
//
#include <hip/hip_runtime.h>

#define NDIM 64
#define NRANK 8
#define NK 16
#define CSTRIDE 641                 // floats per component: 1 + 64 + 512 + 64
#define ROWSTRIDE (CSTRIDE * NK)    // 10256 floats = 41024 B per row

// ---- DPP helpers --------------------------------------------------------

template <int CTRL>
__device__ __forceinline__ float dpp_mov(float x) {
  int t = __builtin_amdgcn_update_dpp(0, __builtin_bit_cast(int, x), CTRL,
                                      0xF, 0xF, true);
  return __builtin_bit_cast(float, t);
}

// sum across the 16-lane group (lane bits 0..3); all 16 lanes get the total
__device__ __forceinline__ void red16(float& x) {
  x += dpp_mov<0xB1>(x);   // quad_perm [1,0,3,2]  == xor 1
  x += dpp_mov<0x4E>(x);   // quad_perm [2,3,0,1]  == xor 2
  x += dpp_mov<0x141>(x);  // row_half_mirror      == xor 4
  x += dpp_mov<0x140>(x);  // row_mirror           == xor 8
}

// ---- kernel -------------------------------------------------------------
// One row per 256-thread block, 8192 independent blocks (block-level
// pipelining across the 3-4 resident blocks/CU). Wave w computes components
// k = 4w..4w+3; 16 lanes per component, dims d = de + 16*i per lane.
// All row data is loaded REGISTER-DIRECT (no LDS staging): per (lane,i) one
// 32 B W chunk (2x dwordx4, 512 B contiguous per 16-lane group) + mu + ld +
// label. 44 data VGPRs/lane = 11 KB in flight per wave, zero bank conflicts,
// exact traffic. LDS is only 32 floats of LSE scratch + one barrier.

__global__ __launch_bounds__(256) void gmm_nll_kernel(
    const float* __restrict__ pred, const float* __restrict__ label,
    float* __restrict__ out, int nb) {
  __shared__ float scratch[32];
  const int tid = threadIdx.x;
  const int w = tid >> 6;       // wave id 0..3
  const int lane = tid & 63;
  const int kk = lane >> 4;     // component within wave
  const int de = lane & 15;     // dim-group within component
  const int b = blockIdx.x;

  const int k = 4 * w + kk;
  const float* comp = pred + (size_t)b * ROWSTRIDE + k * CSTRIDE;
  const float* lbl = label + (size_t)b * NDIM;

  // ---- register-direct loads of everything this lane needs ----
  float w_[4][8];   // W[d][0..7] for d = de + 16*i
  float mu_[4], ld_[4], lb_[4];
#pragma unroll
  for (int i = 0; i < 4; ++i) {
    const int d = de + 16 * i;
    __builtin_memcpy(&w_[i][0], comp + 1 + NDIM + 8 * d, 32);
    mu_[i] = comp[1 + d];
    ld_[i] = comp[1 + NDIM + NDIM * NRANK + d];  // log-diag
    lb_[i] = lbl[d];
  }
  float pi = comp[0];

  // ---- accumulate cap / b / mahal over this lane's 4 dims ----
  float capL[NRANK][NRANK];  // lower triangle (s <= r) used
  float bv[NRANK];
#pragma unroll
  for (int r = 0; r < NRANK; ++r) {
    bv[r] = 0.f;
#pragma unroll
    for (int s = 0; s <= r; ++s) capL[r][s] = 0.f;
  }
  float mahal1 = 0.f, ldsum = 0.f;

#pragma unroll
  for (int i = 0; i < 4; ++i) {
    float ldv = ld_[i];
    float sd = __expf(-0.5f * ldv);  // sqrt(1/d)
    float diff = lb_[i] - mu_[i];
    float u = diff * sd;
    mahal1 = fmaf(u, u, mahal1);
    ldsum += ldv;

    float v[NRANK];
#pragma unroll
    for (int r = 0; r < NRANK; ++r) v[r] = w_[i][r] * sd;
#pragma unroll
    for (int r = 0; r < NRANK; ++r) {
      bv[r] = fmaf(v[r], u, bv[r]);
#pragma unroll
      for (int s = 0; s <= r; ++s)
        capL[r][s] = fmaf(v[r], v[s], capL[r][s]);
    }
  }

  // reduce the 46 partials across the 16 de-lanes
  red16(mahal1);
  red16(ldsum);
#pragma unroll
  for (int r = 0; r < NRANK; ++r) {
    red16(bv[r]);
#pragma unroll
    for (int s = 0; s <= r; ++s) red16(capL[r][s]);
  }

  // cap = I + W^T D^-1 W
#pragma unroll
  for (int r = 0; r < NRANK; ++r) capL[r][r] += 1.0f;

  // in-place Cholesky (lower), fully unrolled; rsqrt + deferred single log
  float invd[NRANK];
  float prodinv = 1.0f;  // prod of 1/L_jj
#pragma unroll
  for (int j = 0; j < NRANK; ++j) {
    float s = capL[j][j];
#pragma unroll
    for (int p = 0; p < j; ++p) s = fmaf(-capL[j][p], capL[j][p], s);
    float inv = __frsqrt_rn(s);  // 1/L_jj
    invd[j] = inv;
    prodinv *= inv;
#pragma unroll
    for (int i2 = j + 1; i2 < NRANK; ++i2) {
      float t = capL[i2][j];
#pragma unroll
      for (int p = 0; p < j; ++p) t = fmaf(-capL[i2][p], capL[j][p], t);
      capL[i2][j] = t * inv;
    }
  }
  float logdetL = -__logf(prodinv);  // sum log(L_jj)

  // forward solve L y = b, accumulate |y|^2
  float y[NRANK];
  float ysq = 0.f;
#pragma unroll
  for (int i2 = 0; i2 < NRANK; ++i2) {
    float t = bv[i2];
#pragma unroll
    for (int j = 0; j < i2; ++j) t = fmaf(-capL[i2][j], y[j], t);
    y[i2] = t * invd[i2];
    ysq = fmaf(y[i2], y[i2], ysq);
  }

  float mahal = mahal1 - ysq;
  float logdet = 2.0f * logdetL + ldsum;
  const float c_dim_log2pi = 117.62413225019810f;  // 64 * log(2*pi)
  float comp_lp = -0.5f * (c_dim_log2pi + logdet + mahal);

  if (de == 0) {
    scratch[k] = pi;
    scratch[16 + k] = pi + comp_lp;
  }
  __syncthreads();

  // final logsumexp over the 16 components (wave 0, lanes 0..15)
  if (tid < 16) {
    float p = scratch[tid];
    float t2 = scratch[16 + tid];

    float m1 = p;
    m1 = fmaxf(m1, dpp_mov<0xB1>(m1));
    m1 = fmaxf(m1, dpp_mov<0x4E>(m1));
    m1 = fmaxf(m1, dpp_mov<0x141>(m1));
    m1 = fmaxf(m1, dpp_mov<0x140>(m1));
    float e1 = __expf(p - m1);
    red16(e1);

    float m2 = t2;
    m2 = fmaxf(m2, dpp_mov<0xB1>(m2));
    m2 = fmaxf(m2, dpp_mov<0x4E>(m2));
    m2 = fmaxf(m2, dpp_mov<0x141>(m2));
    m2 = fmaxf(m2, dpp_mov<0x140>(m2));
    float e2 = __expf(t2 - m2);
    red16(e2);

    if (tid == 0) out[b] = (m1 + __logf(e1)) - (m2 + __logf(e2));
  }
}

extern "C" void kernel_launch(void* const* d_in, const int* in_sizes, int n_in,
                              void* d_out, int out_size, void* d_ws,
                              size_t ws_size, hipStream_t stream) {
  const float* pred = (const float*)d_in[0];
  const float* label = (const float*)d_in[1];
  float* out = (float*)d_out;
  const int nb = out_size;  // 8192
  gmm_nll_kernel<<<dim3(nb), dim3(256), 0, stream>>>(pred, label, out, nb);
}